// Round 1
// baseline (193.230 us; speedup 1.0000x reference)
//
#include <hip/hip_runtime.h>
#include <math.h>

// Fixed-point LeNet, B=2048. R10: three-kernel pipeline.
// k1: conv1+pool1 (unchanged R8/R9 structure) + fc-weight pre-quant prep in block 0.
// k2: conv2+pool2 ONLY, 2 images/block (amortized weight staging, no serial tail).
// k3: fc1+fc2+log_softmax, one wave per image, barrier-free math via shfl;
//     fc1 weights pre-transposed/quantized in d_ws -> coalesced 256B loads.
// Rationale (R10): k2_rest was latency-bound (VALUBusy 35%, Occ 38%) on its
// convoyed low-parallelism tail (fc1 chunk loop, t<50 reduce, t<10 fc2,
// t==0 softmax, 4 barriers) + 1.2e7 LDS bank conflicts (5-way on s_p2 reads).
// Splitting the tail into a wave-parallel kernel removes both.
//
// Output layout (fp32, concatenated flat in reference return order):
//   logp[2048,10], conv1_in[2048,784], conv1_out[2048,5760],
//   conv2_in[2048,1440], conv2_out[2048,1280], fc1_in[2048,320],
//   fc1_out[2048,50], fc2_in[2048,50], fc2_out[2048,10]

#define NB 2048

#define OFF_LOGP   0
#define OFF_C1IN   (OFF_LOGP  + NB*10)
#define OFF_C1OUT  (OFF_C1IN  + NB*784)
#define OFF_C2IN   (OFF_C1OUT + NB*5760)
#define OFF_C2OUT  (OFF_C2IN  + NB*1440)
#define OFF_FC1IN  (OFF_C2OUT + NB*1280)
#define OFF_FC1OUT (OFF_FC1IN + NB*320)
#define OFF_FC2IN  (OFF_FC1OUT+ NB*50)
#define OFF_FC2OUT (OFF_FC2IN + NB*50)

#define MAGIC_F 12582912.0f   // 1.5 * 2^23

// Workspace layout (floats): pre-quantized fc weights.
#define WS_WT1 0         // [320][64] transposed fw1: wT1[k*64+j] = clamp(quant(fw1[j][k])), j>=50 -> 0
#define WS_B1  20480     // [64]
#define WS_WT2 20544     // [50][16] transposed fw2: wT2[k*16+j], j>=10 -> 0
#define WS_B2  21344     // [16]  (total 21360 floats = 85.4 KB)

__device__ __forceinline__ float clamp8(float v) {
    return __builtin_amdgcn_fmed3f(v, -8.0f, 7.0f);
}

// ---------------- K1: conv1 + pool1 (+ fc weight prep in block 0) ----------------
// grid = 2*NB, block = 256. blockIdx>>1 = img, blockIdx&1 = co-half (5 co each).
// 240 active tasks: t = co_l*48 + i*2 + jh. bit1(t)==i&1 -> pool partner t^2.
__global__ __launch_bounds__(256, 3)
void k1_conv1(const float* __restrict__ x,
              const float* __restrict__ cw1, const float* __restrict__ cb1,
              const float* __restrict__ fw1, const float* __restrict__ fb1,
              const float* __restrict__ fw2, const float* __restrict__ fb2,
              float* __restrict__ ws,
              float* __restrict__ out)
{
    __shared__ __align__(16) float s_w1[140];   // [5][28] padded, quant(w)*256
    __shared__ float s_b1[5];
    __shared__ __align__(16) float s_x[784];

    const int t    = threadIdx.x;
    const int img  = blockIdx.x >> 1;
    const int half = blockIdx.x & 1;

    if (t < 125) s_w1[(t / 25) * 28 + (t % 25)] = rintf(cw1[half * 125 + t] * 256.0f);
    if (t < 5)   s_b1[t] = rintf(cb1[half * 5 + t] * 256.0f);

    const float* xg = x + (size_t)img * 784;
    float* c1in_g = out + OFF_C1IN + (size_t)img * 784;
    for (int i = t; i < 784; i += 256) {
        float v = rintf(xg[i] * 256.0f) * (1.0f / 256.0f);
        s_x[i] = v;
        if (half == 0) c1in_g[i] = v;
    }
    __syncthreads();

    if (t < 240) {
        const int co_l = t / 48;
        const int co   = half * 5 + co_l;
        const int r    = t % 48;
        const int i    = r >> 1;
        const int jh   = r & 1;                 // cols [12*jh, 12*jh+12)

        float wreg[28];
        {
            const float* wb = s_w1 + co_l * 28;
            #pragma unroll
            for (int k = 0; k < 7; k++) {
                float4 v4 = *(const float4*)(wb + 4 * k);
                wreg[4*k] = v4.x; wreg[4*k+1] = v4.y; wreg[4*k+2] = v4.z; wreg[4*k+3] = v4.w;
            }
        }

        float acc[12];
        #pragma unroll
        for (int j = 0; j < 12; j++) acc[j] = MAGIC_F;   // magic-biased accumulator

        #pragma unroll
        for (int p = 0; p < 5; p++) {
            float xr[16];
            const float* row = &s_x[(i + p) * 28 + 12 * jh];
            #pragma unroll
            for (int k = 0; k < 4; k++) {
                float4 v4 = *(const float4*)(row + 4 * k);
                xr[4*k] = v4.x; xr[4*k+1] = v4.y; xr[4*k+2] = v4.z; xr[4*k+3] = v4.w;
            }
            #pragma unroll
            for (int q = 0; q < 5; q++) {
                float w = wreg[p * 5 + q];
                #pragma unroll
                for (int j = 0; j < 12; j++)
                    acc[j] = fmaf(xr[q + j], w, acc[j]);   // mul+round+add in 1 op
            }
        }
        const float C = MAGIC_F - s_b1[co_l];   // exact (b256 integer, same exponent)
        float v[12];
        #pragma unroll
        for (int j = 0; j < 12; j++) v[j] = (acc[j] - C) * (1.0f / 256.0f);  // exact grid

        float* gdst = out + OFF_C1OUT + (size_t)img * 5760 + co * 576 + i * 24 + 12 * jh;
        #pragma unroll
        for (int k = 0; k < 3; k++) {
            float4 st = { v[4*k], v[4*k+1], v[4*k+2], v[4*k+3] };
            *(float4*)(gdst + 4 * k) = st;
        }

        float m[6];
        #pragma unroll
        for (int j2 = 0; j2 < 6; j2++) m[j2] = fmaxf(v[2*j2], v[2*j2+1]);
        float pm[6];
        #pragma unroll
        for (int j2 = 0; j2 < 6; j2++) pm[j2] = __shfl_xor(m[j2], 2);

        if ((i & 1) == 0) {
            float pr[6];
            #pragma unroll
            for (int j2 = 0; j2 < 6; j2++)
                pr[j2] = fmaxf(fmaxf(m[j2], pm[j2]), 0.0f);
            float* g = out + OFF_C2IN + (size_t)img * 1440 + co * 144 + (i >> 1) * 12 + 6 * jh;
            #pragma unroll
            for (int k = 0; k < 3; k++) {
                float2 st = { pr[2*k], pr[2*k+1] };
                *(float2*)(g + 2 * k) = st;
            }
        }
    }

    // ---- fc weight pre-quant (block 0 only; hidden under the other 4095 blocks).
    // Stream-ordered: k3 launches two kernels later, so completion is guaranteed.
    if (blockIdx.x == 0) {
        for (int idx = t; idx < 20480; idx += 256) {       // wT1[320][64]
            int k = idx >> 6, j = idx & 63;
            float v = 0.0f;
            if (j < 50) v = clamp8(rintf(fw1[j * 320 + k] * 256.0f) * (1.0f / 256.0f));
            ws[WS_WT1 + idx] = v;
        }
        for (int idx = t; idx < 800; idx += 256) {         // wT2[50][16]
            int k = idx >> 4, j = idx & 15;
            float v = 0.0f;
            if (j < 10) v = clamp8(rintf(fw2[j * 50 + k] * 256.0f) * (1.0f / 256.0f));
            ws[WS_WT2 + idx] = v;
        }
        if (t < 64) ws[WS_B1 + t] = (t < 50) ? clamp8(rintf(fb1[t] * 256.0f) * (1.0f / 256.0f)) : 0.0f;
        if (t < 16) ws[WS_B2 + t] = (t < 10) ? clamp8(rintf(fb2[t] * 256.0f) * (1.0f / 256.0f)) : 0.0f;
    }
}

// ---------------- K2: conv2 + pool2 only ----------------
// block=320 (5 waves), 2 images per block (amortized s_w2 staging), grid=NB/2.
// conv2 task: t -> (co=t/16, i=(t/2)%8, jh=t&1), 4 outputs per thread per image.
// No tail phases, single barrier -> no convoying.
__global__ __launch_bounds__(320)
void k2_conv2(const float* __restrict__ cw2, const float* __restrict__ cb2,
              float* __restrict__ out)
{
    __shared__ __align__(16) float s_w2[5600];     // [co][ci][28] padded rows, x256
    __shared__ float s_b2[20];
    __shared__ __align__(16) float s_p1[2 * 1440]; // conv2 input, 2 images

    const int t    = threadIdx.x;
    const int img0 = blockIdx.x * 2;

    for (int idx = t; idx < 5000; idx += 320) {
        int cc = idx / 25, q = idx % 25;             // cc = co*10+ci
        s_w2[cc * 28 + q] = rintf(cw2[idx] * 256.0f);
    }
    if (t < 20) s_b2[t] = rintf(cb2[t] * 256.0f);

    const float* p1g = out + OFF_C2IN + (size_t)img0 * 1440;   // two contiguous images
    for (int i = t; i < 2880; i += 320) s_p1[i] = p1g[i];
    __syncthreads();

    const int co = t >> 4;
    const int i  = (t >> 1) & 7;
    const int jh = t & 1;              // j base = 4*jh
    const float C2 = MAGIC_F - s_b2[co];

    for (int im = 0; im < 2; im++) {
        const int img = img0 + im;

        float acc[4] = { MAGIC_F, MAGIC_F, MAGIC_F, MAGIC_F };
        for (int ci = 0; ci < 10; ci++) {
            float wreg[28];
            {
                const float* wb = s_w2 + (co * 10 + ci) * 28;
                #pragma unroll
                for (int k = 0; k < 7; k++) {
                    float4 v4 = *(const float4*)(wb + 4 * k);
                    wreg[4*k] = v4.x; wreg[4*k+1] = v4.y; wreg[4*k+2] = v4.z; wreg[4*k+3] = v4.w;
                }
            }
            const float* xb = s_p1 + im * 1440 + ci * 144 + jh * 4;
            #pragma unroll
            for (int p = 0; p < 5; p++) {
                const float* row = xb + (i + p) * 12;
                float4 a4 = *(const float4*)(row);
                float4 b4 = *(const float4*)(row + 4);
                float xr[8] = { a4.x, a4.y, a4.z, a4.w, b4.x, b4.y, b4.z, b4.w };
                #pragma unroll
                for (int q = 0; q < 5; q++) {
                    float w = wreg[p * 5 + q];
                    #pragma unroll
                    for (int j = 0; j < 4; j++)
                        acc[j] = fmaf(xr[q + j], w, acc[j]);   // mul+round+add in 1 op
                }
            }
        }
        float v[4];
        #pragma unroll
        for (int j = 0; j < 4; j++) v[j] = (acc[j] - C2) * (1.0f / 256.0f);  // exact grid

        {   // conv2_output
            float4 st = { v[0], v[1], v[2], v[3] };
            *(float4*)(out + OFF_C2OUT + (size_t)img * 1280 + co * 64 + i * 8 + jh * 4) = st;
        }

        // pool2 via shfl (row pair i, i^1 are lanes t, t^2 — same wave)
        float m0 = fmaxf(v[0], v[1]);
        float m1 = fmaxf(v[2], v[3]);
        float pm0 = __shfl_xor(m0, 2);
        float pm1 = __shfl_xor(m1, 2);
        if ((i & 1) == 0) {
            float r0 = fmaxf(fmaxf(m0, pm0), 0.0f);
            float r1 = fmaxf(fmaxf(m1, pm1), 0.0f);
            int o = co * 16 + (i >> 1) * 4 + jh * 2;   // [co][4][4]
            out[OFF_FC1IN + (size_t)img * 320 + o]     = r0;
            out[OFF_FC1IN + (size_t)img * 320 + o + 1] = r1;
        }
    }
}

// ---------------- K3: fc1 + fc2 + log_softmax, one wave per image ----------------
// block=256 (4 waves = 4 images), grid = NB/4 = 512.
// fc1: lane j<50 owns output j; x broadcast from LDS (same-addr = free),
// weights pre-transposed -> one coalesced 256B load per k. fc2 + softmax via shfl.
__global__ __launch_bounds__(256)
void k3_fc(const float* __restrict__ ws, float* __restrict__ out)
{
    __shared__ float s_x[4][320];

    const int t    = threadIdx.x;
    const int wv   = t >> 6;
    const int lane = t & 63;
    const int img  = blockIdx.x * 4 + wv;

    const float* xg = out + OFF_FC1IN + (size_t)img * 320;   // written by k2
    #pragma unroll
    for (int r = 0; r < 5; r++)
        s_x[wv][lane + 64 * r] = clamp8(xg[lane + 64 * r]);  // round_max(quant(x)) (already on grid)
    __syncthreads();

    // ---- fc1 ----
    float acc = ws[WS_B1 + lane];
    #pragma unroll 8
    for (int k = 0; k < 320; k++)
        acc = fmaf(s_x[wv][k], ws[WS_WT1 + k * 64 + lane], acc);
    float o1 = rintf(clamp8(acc) * 256.0f) * (1.0f / 256.0f);
    float r1 = fmaxf(o1, 0.0f);
    if (lane < 50) {
        out[OFF_FC1OUT + (size_t)img * 50 + lane] = o1;
        out[OFF_FC2IN  + (size_t)img * 50 + lane] = r1;
    }
    float yc = clamp8(r1);                 // valid on lanes 0..49

    // ---- fc2 (y broadcast via shfl with uniform index -> readlane) ----
    float acc2 = ws[WS_B2 + (lane & 15)];
    #pragma unroll 10
    for (int k = 0; k < 50; k++) {
        float yk = __shfl(yc, k);
        acc2 = fmaf(yk, ws[WS_WT2 + k * 16 + (lane & 15)], acc2);
    }
    float o2 = rintf(clamp8(acc2) * 256.0f) * (1.0f / 256.0f);
    if (lane < 10) out[OFF_FC2OUT + (size_t)img * 10 + lane] = o2;

    // ---- log_softmax across lanes 0..9 (16-lane butterfly; group 0 valid) ----
    float v = (lane < 10) ? o2 : -3.0e38f;
    #pragma unroll
    for (int d = 1; d < 16; d <<= 1)
        v = fmaxf(v, __shfl_xor(v, d, 16));
    float e = (lane < 10) ? expf(o2 - v) : 0.0f;
    #pragma unroll
    for (int d = 1; d < 16; d <<= 1)
        e += __shfl_xor(e, d, 16);
    float lse = v + logf(e);
    if (lane < 10) out[OFF_LOGP + (size_t)img * 10 + lane] = o2 - lse;
}

extern "C" void kernel_launch(void* const* d_in, const int* in_sizes, int n_in,
                              void* d_out, int out_size, void* d_ws, size_t ws_size,
                              hipStream_t stream) {
    const float* x   = (const float*)d_in[0];
    const float* cw1 = (const float*)d_in[1];
    const float* cb1 = (const float*)d_in[2];
    const float* cw2 = (const float*)d_in[3];
    const float* cb2 = (const float*)d_in[4];
    const float* fw1 = (const float*)d_in[5];
    const float* fb1 = (const float*)d_in[6];
    const float* fw2 = (const float*)d_in[7];
    const float* fb2 = (const float*)d_in[8];
    float* o  = (float*)d_out;
    float* ws = (float*)d_ws;

    k1_conv1<<<2 * NB, 256, 0, stream>>>(x, cw1, cb1, fw1, fb1, fw2, fb2, ws, o);
    k2_conv2<<<NB / 2, 320, 0, stream>>>(cw2, cb2, o);
    k3_fc   <<<NB / 4, 256, 0, stream>>>(ws, o);
}